// Round 11
// baseline (232.095 us; speedup 1.0000x reference)
//
#include <hip/hip_runtime.h>
#include <hip/hip_bf16.h>

#define EMBED 128
#define TSTEPS 128
#define NBATCH 32
#define VDIM 50257
#define VPAD 50304            // 3144 16-col chunks
#define MROWS 4096            // NBATCH * TSTEPS
#define NCHK (VPAD / 16)      // 3144
#define GX 12                 // x blocks; 48 wave-columns
#define GY 64                 // 64-row M slices
#define CONV_N4 ((VDIM * EMBED) / 4)            // 1608224 float4 elements
#define CONV_BLOCKS ((CONV_N4 + 127) / 128)     // 12565 (128-thread blocks)

static constexpr float LOG2E = 1.4426950408889634f;
static constexpr float LN2   = 0.6931471805599453f;

__device__ __forceinline__ float fast_exp2(float x) {
#if __has_builtin(__builtin_amdgcn_exp2f)
    return __builtin_amdgcn_exp2f(x);
#else
    return exp2f(x);
#endif
}
__device__ __forceinline__ float fast_log2(float x) {
#if __has_builtin(__builtin_amdgcn_logf)
    return __builtin_amdgcn_logf(x);
#else
    return log2f(x);
#endif
}
__device__ __forceinline__ unsigned short f2bf_raw(float f) {
    __hip_bfloat16 h = __float2bfloat16(f);
    union { __hip_bfloat16 b; unsigned short u; } cvt;
    cvt.b = h;
    return cvt.u;
}
__device__ __forceinline__ float bf_raw2f(unsigned short u) {
    union { unsigned int u; float f; } cvt;
    cvt.u = ((unsigned int)u) << 16;
    return cvt.f;
}

// s_waitcnt immediates (gfx9 encoding): vmcnt[3:0] | expcnt=7<<4 | lgkmcnt=15<<8
#define WAITCNT_VM10 0xF7A
#define WAITCNT_VM5  0xF75
#define WAITCNT_VM0  0xF70

// ---------------------------------------------------------------------------
// K0 (fused setup), 128-thread blocks: blocks [0,32) = sequential scan (one
// batch chain each); blocks [32, 32+CONV_BLOCKS) convert Wv fp32->bf16
// (+ zero pad rows), build ebt[j] = exp2(bv[j]*log2e) (pad -> 0), zero S.
//
// Scan (round-11 restructure, BIT-EXACT trajectory): 128 threads, e = tid;
// each lane computes BOTH k-halves of its own element in the identical fp
// op order as rounds 1/3/5-10: vA = chain(k 0..63), vB = chain(k 64..127),
// znew = tanhf(((zc+vA)+vB)+bt) — same ops, same order, no shfl, 2-wave
// barrier instead of 4.  Per-step bf16 emission goes to a 32 KB LDS stash
// (lgkmcnt-only barrier), bulk-stored at the end.  libm tanhf mandatory
// (round-4: 1e-6/step approximations amplify to ~0.2 absmax).
// NOTE (round-9): no cross-block producer/consumer sync — device-scope
// fences force L2 writeback/invalidate (5.6x regression).
// ---------------------------------------------------------------------------
__global__ __launch_bounds__(128) void setup_kernel(const int* __restrict__ zi,
                                                    const float* __restrict__ latent,
                                                    const float* __restrict__ Wt,
                                                    const float* __restrict__ bt,
                                                    const float* __restrict__ Wv,
                                                    const float* __restrict__ bv,
                                                    unsigned short* __restrict__ zsb,
                                                    unsigned short* __restrict__ Wvb,
                                                    float* __restrict__ ebt,
                                                    float* __restrict__ S) {
    if (blockIdx.x >= NBATCH) {
        const int cb = blockIdx.x - NBATCH;
        if (cb == 0) {                      // zero the S accumulator
#pragma unroll
            for (int i = 0; i < MROWS / 128; i++)
                S[i * 128 + threadIdx.x] = 0.f;
        }
        if (cb == 1) {                      // zero bf16 pad rows of Wvb
            const int base4 = (VDIM * EMBED) / 4;
            const int npad4 = ((VPAD - VDIM) * EMBED) / 4;
            for (int i = threadIdx.x; i < npad4; i += 128)
                reinterpret_cast<ushort4*>(Wvb)[base4 + i] = make_ushort4(0, 0, 0, 0);
        }
        const int idx = cb * 128 + threadIdx.x;
        if (idx < VPAD)                     // ebt = e^bv (pad -> 0)
            ebt[idx] = (idx < VDIM) ? fast_exp2(bv[idx] * LOG2E) : 0.f;
        if (idx < CONV_N4) {
            float4 v = reinterpret_cast<const float4*>(Wv)[idx];
            ushort4 o;
            o.x = f2bf_raw(v.x); o.y = f2bf_raw(v.y);
            o.z = f2bf_raw(v.z); o.w = f2bf_raw(v.w);
            reinterpret_cast<ushort4*>(Wvb)[idx] = o;
        }
        return;
    }

    // ---- scan path: one block (128 threads) per batch element ----
    __shared__ float zbuf[2][EMBED];
    __shared__ unsigned short zstash[TSTEPS * EMBED];   // 32 KB bf16 stash
    const int b = blockIdx.x;
    const int e = threadIdx.x;          // output element 0..127

    // cache the FULL Wt row e in registers (128 VGPRs)
    float4 wrowA[16], wrowB[16];
    const float4* wt4 = reinterpret_cast<const float4*>(Wt + e * EMBED);
#pragma unroll
    for (int i = 0; i < 16; i++) wrowA[i] = wt4[i];
#pragma unroll
    for (int i = 0; i < 16; i++) wrowB[i] = wt4[16 + i];
    const float bte = bt[e];

    zbuf[0][e] = latent[zi[b] * EMBED + e];
    __syncthreads();

    int cur = 0;
    for (int t = 0; t < TSTEPS; t++) {
        const float zc = zbuf[cur][e];
        zstash[t * EMBED + e] = f2bf_raw(zc * LOG2E);   // stash (LDS only)

        // half-dot A: k in [0,64)  — op order identical to rounds 1..10
        const float4* z4 = reinterpret_cast<const float4*>(&zbuf[cur][0]);
        float4 accA = {0.f, 0.f, 0.f, 0.f};
#pragma unroll
        for (int i = 0; i < 16; i++) {
            float4 zv = z4[i];
            accA.x += zv.x * wrowA[i].x;
            accA.y += zv.y * wrowA[i].y;
            accA.z += zv.z * wrowA[i].z;
            accA.w += zv.w * wrowA[i].w;
        }
        float vA = accA.x + accA.y + accA.z + accA.w;
        // half-dot B: k in [64,128)
        float4 accB = {0.f, 0.f, 0.f, 0.f};
#pragma unroll
        for (int i = 0; i < 16; i++) {
            float4 zv = z4[16 + i];
            accB.x += zv.x * wrowB[i].x;
            accB.y += zv.y * wrowB[i].y;
            accB.z += zv.z * wrowB[i].z;
            accB.w += zv.w * wrowB[i].w;
        }
        float vB = accB.x + accB.y + accB.z + accB.w;

        float znew = tanhf(((zc + vA) + vB) + bte);   // exact libm tanh
        zbuf[cur ^ 1][e] = znew;
        __syncthreads();                    // 2-wave barrier, lgkmcnt-only
        cur ^= 1;
    }

    // bulk store: 32 KB contiguous (rows b*128..b*128+127), coalesced
    uint4* dst = reinterpret_cast<uint4*>(zsb + (long)b * TSTEPS * EMBED);
    const uint4* src = reinterpret_cast<const uint4*>(zstash);
    for (int i = threadIdx.x; i < TSTEPS * EMBED / 8; i += 128)
        dst[i] = src[i];
}

// ---------------------------------------------------------------------------
// K1 (round-11 restructure): BARRIER-FREE fused GEMM + sum-of-exp2.
// The m97-style barrier K-loop plateaued at ~74us across R6-R10 (MFMA busy
// time already = 21us theoretical min; ~50us was barrier-synchronized
// stall).  New structure: block = 64 M-rows shared by 4 waves; each WAVE
// owns a private column range (48 wave-cols x ~65 16-col chunks) and a
// private 3-deep LDS ring (3 x 4KB).  No __syncthreads in the K-loop: a
// wave stages its own B-chunk via global_load_lds (4 x 1KB, XOR-16 granule
// swizzle -> conflict-free ds_read_b128, verified 0 conflicts R6-R10) plus
// one e^bias load (5 VMEM ops/iter), prefetch depth 2, and gates compute
// with manual s_waitcnt vmcnt(10) (tail peel: 5, then 0).  exp2 of iter i
// overlaps MFMAs of iter i+1 — nothing blocks the scheduler.
// 48KB LDS/block -> exactly 3 blocks/CU; grid 12x64 = 768 blocks = one full
// residency pass (12 waves/CU).
// mfma_f32_16x16x32_bf16 layouts (HW-verified, guide §3):
//   A: lane holds A[m=lane&15][k=(lane>>4)*8 + j], j=0..7
//   B: lane holds B[n=lane&15][k=(lane>>4)*8 + j]
//   D: lane holds D[row=(lane>>4)*4 + r][col=lane&15], r=0..3
// ---------------------------------------------------------------------------
typedef __attribute__((ext_vector_type(8))) short bfrag;
typedef __attribute__((ext_vector_type(4))) float f32x4;

__global__ __launch_bounds__(256) void gemm_lse_kernel(const unsigned short* __restrict__ zsb,
                                                       const unsigned short* __restrict__ Wvb,
                                                       const float* __restrict__ ebt,
                                                       float* __restrict__ S) {
    __shared__ short ldsw[4][3][2048];       // per-wave 3-deep ring, 4KB bufs

    const int lane  = threadIdx.x & 63;
    const int wave  = threadIdx.x >> 6;
    const int col16 = lane & 15;
    const int quad  = lane >> 4;
    const int mbase = blockIdx.y * 64;       // all 4 waves: same 64 M-rows

    // wave-column range: 3144 chunks over 48 wave-cols: 24 get 66, rest 65
    const int w    = blockIdx.x * 4 + wave;
    const int c0   = w * 65 + min(w, 24);
    const int cnt  = 65 + (w < 24 ? 1 : 0);

    // A fragments: 4 M-subtiles x 4 K-chunks, register resident (64 VGPRs)
    bfrag a[4][4];
    const short* zss = reinterpret_cast<const short*>(zsb);
#pragma unroll
    for (int s = 0; s < 4; s++)
#pragma unroll
        for (int c = 0; c < 4; c++) {
            const short* p = zss + (long)(mbase + s * 16 + col16) * EMBED + c * 32 + quad * 8;
            a[s][c] = *reinterpret_cast<const bfrag*>(p);
        }

    float sums[16];
#pragma unroll
    for (int i = 0; i < 16; i++) sums[i] = 0.f;

    const short* wvs = reinterpret_cast<const short*>(Wvb);
    short* wbase = &ldsw[wave][0][0];

    // stage chunk chk (16 B-rows x 128 k) into this wave's ring buffer buf
    auto stage = [&](int buf, int chk) {
        short* dst = wbase + buf * 2048;
#pragma unroll
        for (int j = 0; j < 4; j++) {
            const int r   = j * 4 + quad;              // B-row within chunk
            const int swz = col16 ^ r;                 // XOR-16 granule swizzle
            const short* gp = wvs + (long)(chk * 16 + r) * EMBED + swz * 8;
            __builtin_amdgcn_global_load_lds(
                (const __attribute__((address_space(1))) void*)gp,
                (__attribute__((address_space(3))) void*)(dst + j * 512),
                16, 0, 0);
        }
    };

    // compute one chunk from ring buffer buf with bias factor eb
    auto body = [&](int buf, float eb) {
        const short* src = wbase + buf * 2048;
        bfrag bf[4];
#pragma unroll
        for (int kc = 0; kc < 4; kc++)
            bf[kc] = *reinterpret_cast<const bfrag*>(
                src + col16 * 128 + (((kc * 4 + quad) ^ col16) * 8));

        const f32x4 dzero = {0.f, 0.f, 0.f, 0.f};
        f32x4 d[4];
#pragma unroll
        for (int s = 0; s < 4; s++)
            d[s] = __builtin_amdgcn_mfma_f32_16x16x32_bf16(a[s][0], bf[0], dzero, 0, 0, 0);
#pragma unroll
        for (int kc = 1; kc < 4; kc++)
#pragma unroll
            for (int s = 0; s < 4; s++)
                d[s] = __builtin_amdgcn_mfma_f32_16x16x32_bf16(a[s][kc], bf[kc], d[s], 0, 0, 0);

#pragma unroll
        for (int s = 0; s < 4; s++)
#pragma unroll
            for (int r = 0; r < 4; r++)
                sums[s * 4 + r] = fmaf(fast_exp2(d[s][r]), eb, sums[s * 4 + r]);
    };

    // prologue: stage chunks c0, c0+1 (+ their bias factors) — 5 ops each
    stage(0, c0);
    float ebl0 = ebt[c0 * 16 + col16];
    stage(1, c0 + 1);
    float ebl1 = ebt[(c0 + 1) * 16 + col16];

    int b0 = 0, b1 = 1, b2 = 2;
    for (int i = 0; i < cnt - 2; i++) {
        stage(b2, c0 + i + 2);                          // 4 ops
        float ebl2 = ebt[(c0 + i + 2) * 16 + col16];    // 1 op
        __builtin_amdgcn_s_waitcnt(WAITCNT_VM10);       // chunk i's 5 ops done
        body(b0, ebl0);
        ebl0 = ebl1; ebl1 = ebl2;
        int tmp = b0; b0 = b1; b1 = b2; b2 = tmp;
    }
    __builtin_amdgcn_s_waitcnt(WAITCNT_VM5);            // chunk cnt-2 done
    body(b0, ebl0);
    __builtin_amdgcn_s_waitcnt(WAITCNT_VM0);            // chunk cnt-1 done
    body(b1, ebl1);

    // reduce partial sums over the 16 columns, one atomic per row per wave
#pragma unroll
    for (int s = 0; s < 4; s++) {
#pragma unroll
        for (int r = 0; r < 4; r++) {
            float v = sums[s * 4 + r];
            v += __shfl_xor(v, 1);
            v += __shfl_xor(v, 2);
            v += __shfl_xor(v, 4);
            v += __shfl_xor(v, 8);
            if (col16 == 0)
                atomicAdd(&S[mbase + s * 16 + quad * 4 + r], v);
        }
    }
}

// ---------------------------------------------------------------------------
// K2: yp[row] = ln2*(dot_scaled - log2(S[row])) + bv[y[row]], where
// dot_scaled = (bf16 zsb row) . (fp32 Wv[y] row)  -- zsb is z*log2e in bf16;
// bf16 quantization adds only ~1e-3 to the target dot (budget 0.156).
// One wave per row; lane l handles elements {2l, 2l+1}.
// ---------------------------------------------------------------------------
__global__ __launch_bounds__(256) void tail_kernel(const unsigned short* __restrict__ zsb,
                                                   const float* __restrict__ Wv,
                                                   const float* __restrict__ bv,
                                                   const int* __restrict__ y,
                                                   const float* __restrict__ S,
                                                   float* __restrict__ out) {
    const int row  = blockIdx.x * 4 + (threadIdx.x >> 6);
    const int lane = threadIdx.x & 63;
    const int yv = y[row];
    const ushort2* zr = reinterpret_cast<const ushort2*>(zsb + (long)row * EMBED);
    const float2*  wr = reinterpret_cast<const float2*>(Wv + (long)yv * EMBED);
    ushort2 z2 = zr[lane];
    float2  w2 = wr[lane];
    float v = bf_raw2f(z2.x) * w2.x + bf_raw2f(z2.y) * w2.y;
    v += __shfl_xor(v, 32);
    v += __shfl_xor(v, 16);
    v += __shfl_xor(v, 8);
    v += __shfl_xor(v, 4);
    v += __shfl_xor(v, 2);
    v += __shfl_xor(v, 1);
    if (lane == 0)
        out[row] = LN2 * (v - fast_log2(S[row])) + bv[yv];
}

// ---------------------------------------------------------------------------
extern "C" void kernel_launch(void* const* d_in, const int* in_sizes, int n_in,
                              void* d_out, int out_size, void* d_ws, size_t ws_size,
                              hipStream_t stream) {
    const int*   zi     = (const int*)d_in[0];
    const int*   y      = (const int*)d_in[1];
    const float* latent = (const float*)d_in[2];
    const float* Wt     = (const float*)d_in[3];
    const float* bt     = (const float*)d_in[4];
    const float* Wv     = (const float*)d_in[5];
    const float* bv     = (const float*)d_in[6];
    float* out = (float*)d_out;

    char* ws = (char*)d_ws;
    // workspace layout (~14.3 MB total):
    unsigned short* zsb = (unsigned short*)ws;                         // 1 MB   @ 0
    float*          S   = (float*)(ws + (1u << 20));                   // 16 KB  @ 1M
    float*          ebt = (float*)(ws + (1u << 20) + (64u << 10));     // 197 KB @ 1M+64K
    unsigned short* wvb = (unsigned short*)(ws + (2u << 20));          // 12.28MB@ 2M

    setup_kernel<<<NBATCH + CONV_BLOCKS, 128, 0, stream>>>(zi, latent, Wt, bt, Wv, bv,
                                                           zsb, wvb, ebt, S);

    gemm_lse_kernel<<<dim3(GX, GY), 256, 0, stream>>>(zsb, wvb, ebt, S);

    tail_kernel<<<MROWS / 4, 256, 0, stream>>>(zsb, Wv, bv, y, S, out);
}

// Round 12
// 206.380 us; speedup vs baseline: 1.1246x; 1.1246x over previous
//
#include <hip/hip_runtime.h>
#include <hip/hip_bf16.h>

#define EMBED 128
#define TSTEPS 128
#define NBATCH 32
#define VDIM 50257
#define VPAD 50304            // 786 groups * 64 cols
#define MROWS 4096            // NBATCH * TSTEPS
#define NGROUPS 786           // VPAD / 64
#define GRIDX 64              // B-sweep split: 786 = 64*12 + 18
#define GRIDY 16              // 256-row M slices
#define MAXGRP 13             // max groups per x-block
#define CONV_N4 ((VDIM * EMBED) / 4)          // 1608224 float4 elements
#define CONV_BLOCKS ((CONV_N4 + 255) / 256)   // 6283

static constexpr float LOG2E = 1.4426950408889634f;
static constexpr float LN2   = 0.6931471805599453f;

__device__ __forceinline__ float fast_exp2(float x) {
#if __has_builtin(__builtin_amdgcn_exp2f)
    return __builtin_amdgcn_exp2f(x);
#else
    return exp2f(x);
#endif
}
__device__ __forceinline__ float fast_log2(float x) {
#if __has_builtin(__builtin_amdgcn_logf)
    return __builtin_amdgcn_logf(x);
#else
    return log2f(x);
#endif
}
__device__ __forceinline__ float fast_rcp(float x) {
#if __has_builtin(__builtin_amdgcn_rcpf)
    return __builtin_amdgcn_rcpf(x);
#else
    return 1.0f / x;
#endif
}
// Branch-free tanh with Newton-refined reciprocal.
// R4's fast_tanh (no Newton) drifted +0.19 absmax over 128 recurrence steps
// (per-step err ~2.4e-7: exp2 1ulp + rcp 1ulp).  The Newton step removes
// the rcp term -> per-step ~1.2e-7 -> predicted drift ~0.09 (budget 0.156).
// Clamp |x|<=20: tanh saturates to +-1.0f there anyway; avoids inf*0 NaN.
__device__ __forceinline__ float fast_tanh_nr(float x) {
    x = fminf(20.0f, fmaxf(-20.0f, x));
    float t = fast_exp2((2.0f * LOG2E) * x);    // e^{2x}
    float u = t + 1.0f;
    float r = fast_rcp(u);                      // ~1 ulp
    r = r * fmaf(-u, r, 2.0f);                  // Newton: error ~ulp^2
    return (t - 1.0f) * r;
}
__device__ __forceinline__ unsigned short f2bf_raw(float f) {
    __hip_bfloat16 h = __float2bfloat16(f);
    union { __hip_bfloat16 b; unsigned short u; } cvt;
    cvt.b = h;
    return cvt.u;
}
__device__ __forceinline__ float bf_raw2f(unsigned short u) {
    union { unsigned int u; float f; } cvt;
    cvt.u = ((unsigned int)u) << 16;
    return cvt.f;
}

// ---------------------------------------------------------------------------
// K0 (fused setup): blocks [0,32) = sequential scan (one batch chain each);
// blocks [32, 32+CONV_BLOCKS) convert Wv fp32->bf16 (+ zero pad rows), build
// bvs[j] = bv[j]*log2e (pad -> -1e30), and zero S.
//
// Scan = R10's 256-thread structure (e = tid>>1, h = tid&1, one shfl_xor,
// ping-pong z, ONE barrier/step, 32 KB LDS stash -> bulk store).  The fp32
// summation order ((zc+sA)+sB)+bt is IDENTICAL to rounds 1-11.  The ONLY
// change this round: tanhf -> fast_tanh_nr (branch-free; libm tanhf's
// divergent poly/exp paths cost ~400-600 cyc/step).
// NOTE (round-9): no cross-block producer/consumer sync — device-scope
// fences force L2 writeback/invalidate (5.6x regression).
// ---------------------------------------------------------------------------
__global__ __launch_bounds__(256) void setup_kernel(const int* __restrict__ zi,
                                                    const float* __restrict__ latent,
                                                    const float* __restrict__ Wt,
                                                    const float* __restrict__ bt,
                                                    const float* __restrict__ Wv,
                                                    const float* __restrict__ bv,
                                                    unsigned short* __restrict__ zsb,
                                                    unsigned short* __restrict__ Wvb,
                                                    float* __restrict__ bvs,
                                                    float* __restrict__ S) {
    if (blockIdx.x >= NBATCH) {
        const int cb = blockIdx.x - NBATCH;
        if (cb == 0) {                      // zero the S accumulator
#pragma unroll
            for (int i = 0; i < MROWS / 256; i++)
                S[i * 256 + threadIdx.x] = 0.f;
        }
        if (cb == 1) {                      // zero bf16 pad rows of Wvb
            const int base4 = (VDIM * EMBED) / 4;
            const int npad4 = ((VPAD - VDIM) * EMBED) / 4;
            for (int i = threadIdx.x; i < npad4; i += 256)
                reinterpret_cast<ushort4*>(Wvb)[base4 + i] = make_ushort4(0, 0, 0, 0);
        }
        const int idx = cb * 256 + threadIdx.x;
        if (idx < VPAD)                     // prescaled, padded bias
            bvs[idx] = (idx < VDIM) ? bv[idx] * LOG2E : -1e30f;
        if (idx < CONV_N4) {
            float4 v = reinterpret_cast<const float4*>(Wv)[idx];
            ushort4 o;
            o.x = f2bf_raw(v.x); o.y = f2bf_raw(v.y);
            o.z = f2bf_raw(v.z); o.w = f2bf_raw(v.w);
            reinterpret_cast<ushort4*>(Wvb)[idx] = o;
        }
        return;
    }

    // ---- scan path: one block per batch element ----
    __shared__ float zbuf[2][EMBED];
    __shared__ unsigned short zstash[TSTEPS * EMBED];   // 32 KB bf16 stash
    const int b = blockIdx.x;
    const int e = threadIdx.x >> 1;     // output element 0..127
    const int h = threadIdx.x & 1;      // k-half

    // cache Wt[e][h*64 .. h*64+63] in registers (64 VGPRs)
    float4 wrow[16];
    const float4* wt4 = reinterpret_cast<const float4*>(Wt + e * EMBED + h * 64);
#pragma unroll
    for (int i = 0; i < 16; i++) wrow[i] = wt4[i];
    const float bte = bt[e];

    if (h == 0) zbuf[0][e] = latent[zi[b] * EMBED + e];
    __syncthreads();

    int cur = 0;
    for (int t = 0; t < TSTEPS; t++) {
        const float zc = zbuf[cur][e];      // lane pairs broadcast
        if (h == 0)                         // stash pre-update z (bf16 * log2e)
            zstash[t * EMBED + e] = f2bf_raw(zc * LOG2E);

        // half-dot over k in [h*64, h*64+64)
        const float4* z4 = reinterpret_cast<const float4*>(&zbuf[cur][h * 64]);
        float4 acc = {0.f, 0.f, 0.f, 0.f};
#pragma unroll
        for (int i = 0; i < 16; i++) {
            float4 zv = z4[i];
            acc.x += zv.x * wrow[i].x;
            acc.y += zv.y * wrow[i].y;
            acc.z += zv.z * wrow[i].z;
            acc.w += zv.w * wrow[i].w;
        }
        float v = acc.x + acc.y + acc.z + acc.w;
        float p = __shfl_xor(v, 1);         // partner half (same e, other h)
        float sA = h ? p : v;
        float sB = h ? v : p;
        // summation order identical to rounds 1-11 (same dot trajectory);
        // the ONLY numeric change is the tanh implementation.
        float znew = fast_tanh_nr(((zc + sA) + sB) + bte);
        if (h == 0) zbuf[cur ^ 1][e] = znew;
        __syncthreads();                    // lgkmcnt-only drain (no stores)
        cur ^= 1;
    }

    // bulk store: 32 KB contiguous (rows b*128..b*128+127), coalesced
    uint4* dst = reinterpret_cast<uint4*>(zsb + (long)b * TSTEPS * EMBED);
    const uint4* src = reinterpret_cast<const uint4*>(zstash);
    for (int i = threadIdx.x; i < TSTEPS * EMBED / 8; i += 256)
        dst[i] = src[i];
}

// ---------------------------------------------------------------------------
// K1: R7-verbatim fused GEMM + sum-of-exp2 (73.5-74.0 us measured, best).
// A = zsb [4096 x 128] bf16 (prescaled by log2e), register-resident per wave.
// B = Wvb [VPAD x 128] bf16 (zero-padded).  Block: 4 waves x 64 rows = 256
// rows x 12-13 groups of 64 N-cols; 16 KB B-tiles DMAd to LDS via
// global_load_lds w=16 with XOR-16 granule swizzle (0 bank conflicts,
// verified R6-R10), double-buffered, one barrier per group; bias slice in
// LDS; zero-C MFMA init; bias via sums = fma(exp2(d), exp2(bias), sums).
// R10/R11 lessons: GRIDX=128 regresses (fixed cost + atomics, no occupancy
// gain); 64-row M-slices regress (4x B traffic).  Keep 256-row slices.
// mfma_f32_16x16x32_bf16 layouts (HW-verified, guide §3):
//   A: lane holds A[m=lane&15][k=(lane>>4)*8 + j], j=0..7
//   B: lane holds B[n=lane&15][k=(lane>>4)*8 + j]
//   D: lane holds D[row=(lane>>4)*4 + r][col=lane&15], r=0..3
// ---------------------------------------------------------------------------
typedef __attribute__((ext_vector_type(8))) short bfrag;
typedef __attribute__((ext_vector_type(4))) float f32x4;

__global__ __launch_bounds__(256) void gemm_lse_kernel(const unsigned short* __restrict__ zsb,
                                                       const unsigned short* __restrict__ Wvb,
                                                       const float* __restrict__ bvs,
                                                       float* __restrict__ S) {
    __shared__ short ldsb[2][8192];          // 2 x 16 KB B tiles
    __shared__ float ldsbias[MAXGRP * 64];   // this block's bias slice (3.3 KB)

    const int lane  = threadIdx.x & 63;
    const int wave  = threadIdx.x >> 6;
    const int col16 = lane & 15;
    const int quad  = lane >> 4;
    const int mbase = blockIdx.y * 256 + wave * 64;

    // group range for this x-block: 786 = 64*12 + 18
    const int x  = blockIdx.x;
    const int g0 = x * 12 + min(x, 18);
    const int g1 = g0 + 12 + (x < 18 ? 1 : 0);
    const int nbias = (g1 - g0) * 64;

    // prologue: stage this block's bias slice into LDS
    for (int i = threadIdx.x; i < nbias; i += 256)
        ldsbias[i] = bvs[g0 * 64 + i];

    // A fragments: 4 M-subtiles x 4 K-chunks, register resident (64 VGPRs)
    bfrag a[4][4];
    const short* zss = reinterpret_cast<const short*>(zsb);
#pragma unroll
    for (int s = 0; s < 4; s++)
#pragma unroll
        for (int c = 0; c < 4; c++) {
            const short* p = zss + (long)(mbase + s * 16 + col16) * EMBED + c * 32 + quad * 8;
            a[s][c] = *reinterpret_cast<const bfrag*>(p);
        }

    float sums[16];
#pragma unroll
    for (int i = 0; i < 16; i++) sums[i] = 0.f;

    const short* wvs = reinterpret_cast<const short*>(Wvb);

    // stage group g's 16 KB B-tile into ldsb[buf] (swizzled, coalesced)
    auto stage = [&](int buf, int g) {
#pragma unroll
        for (int j = 0; j < 4; j++) {
            const int r   = (wave * 4 + j) * 4 + quad;
            const int swz = col16 ^ (r & 15);          // XOR-16 granule swizzle
            const short* gp = wvs + (long)(g * 64 + r) * EMBED + swz * 8;
            __builtin_amdgcn_global_load_lds(
                (const __attribute__((address_space(1))) void*)gp,
                (__attribute__((address_space(3))) void*)&ldsb[buf][(wave * 4 + j) * 512],
                16, 0, 0);
        }
    };

    int cur = 0;
    stage(0, g0);

    const f32x4 dzero = {0.f, 0.f, 0.f, 0.f};

    for (int g = g0; g < g1; g++) {
        __syncthreads();                     // buf[cur] + bias staged; prev reads done
        if (g + 1 < g1) stage(cur ^ 1, g + 1);

        const float* biasg = &ldsbias[(g - g0) * 64];

#pragma unroll
        for (int c = 0; c < 4; c++) {
            // fragment reads: logical (r = c*16+col16, kpart = kc*4+quad),
            // physical col = kpart ^ (r&15) = kpart ^ col16
            bfrag bf[4];
#pragma unroll
            for (int kc = 0; kc < 4; kc++)
                bf[kc] = *reinterpret_cast<const bfrag*>(
                    &ldsb[cur][(c * 16 + col16) * 128 + (((kc * 4 + quad) ^ col16) * 8)]);

            const float eb = fast_exp2(biasg[c * 16 + col16]);  // 0 for pad

            // kc-outer, s-inner: consecutive MFMAs are independent (4 chains)
            f32x4 d[4];
#pragma unroll
            for (int s = 0; s < 4; s++)
                d[s] = __builtin_amdgcn_mfma_f32_16x16x32_bf16(a[s][0], bf[0], dzero, 0, 0, 0);
#pragma unroll
            for (int kc = 1; kc < 4; kc++)
#pragma unroll
                for (int s = 0; s < 4; s++)
                    d[s] = __builtin_amdgcn_mfma_f32_16x16x32_bf16(a[s][kc], bf[kc], d[s], 0, 0, 0);

#pragma unroll
            for (int s = 0; s < 4; s++)
#pragma unroll
                for (int r = 0; r < 4; r++)
                    sums[s * 4 + r] = fmaf(fast_exp2(d[s][r]), eb, sums[s * 4 + r]);
        }
        cur ^= 1;
    }

    // reduce partial sums over the 16 columns, one atomic per row per block
#pragma unroll
    for (int s = 0; s < 4; s++) {
#pragma unroll
        for (int r = 0; r < 4; r++) {
            float v = sums[s * 4 + r];
            v += __shfl_xor(v, 1);
            v += __shfl_xor(v, 2);
            v += __shfl_xor(v, 4);
            v += __shfl_xor(v, 8);
            if (col16 == 0)
                atomicAdd(&S[mbase + s * 16 + quad * 4 + r], v);
        }
    }
}

// ---------------------------------------------------------------------------
// K2: yp[row] = ln2*(dot_scaled - log2(S[row])) + bv[y[row]], where
// dot_scaled = (bf16 zsb row) . (fp32 Wv[y] row)  -- zsb is z*log2e in bf16;
// bf16 quantization adds only ~1e-3 to the target dot.
// One wave per row; lane l handles elements {2l, 2l+1}.
// ---------------------------------------------------------------------------
__global__ __launch_bounds__(256) void tail_kernel(const unsigned short* __restrict__ zsb,
                                                   const float* __restrict__ Wv,
                                                   const float* __restrict__ bv,
                                                   const int* __restrict__ y,
                                                   const float* __restrict__ S,
                                                   float* __restrict__ out) {
    const int row  = blockIdx.x * 4 + (threadIdx.x >> 6);
    const int lane = threadIdx.x & 63;
    const int yv = y[row];
    const ushort2* zr = reinterpret_cast<const ushort2*>(zsb + (long)row * EMBED);
    const float2*  wr = reinterpret_cast<const float2*>(Wv + (long)yv * EMBED);
    ushort2 z2 = zr[lane];
    float2  w2 = wr[lane];
    float v = bf_raw2f(z2.x) * w2.x + bf_raw2f(z2.y) * w2.y;
    v += __shfl_xor(v, 32);
    v += __shfl_xor(v, 16);
    v += __shfl_xor(v, 8);
    v += __shfl_xor(v, 4);
    v += __shfl_xor(v, 2);
    v += __shfl_xor(v, 1);
    if (lane == 0)
        out[row] = LN2 * (v - fast_log2(S[row])) + bv[yv];
}

// ---------------------------------------------------------------------------
extern "C" void kernel_launch(void* const* d_in, const int* in_sizes, int n_in,
                              void* d_out, int out_size, void* d_ws, size_t ws_size,
                              hipStream_t stream) {
    const int*   zi     = (const int*)d_in[0];
    const int*   y      = (const int*)d_in[1];
    const float* latent = (const float*)d_in[2];
    const float* Wt     = (const float*)d_in[3];
    const float* bt     = (const float*)d_in[4];
    const float* Wv     = (const float*)d_in[5];
    const float* bv     = (const float*)d_in[6];
    float* out = (float*)d_out;

    char* ws = (char*)d_ws;
    // workspace layout (~14.3 MB total):
    unsigned short* zsb = (unsigned short*)ws;                         // 1 MB   @ 0
    float*          S   = (float*)(ws + (1u << 20));                   // 16 KB  @ 1M
    float*          bvs = (float*)(ws + (1u << 20) + (64u << 10));     // 197 KB @ 1M+64K
    unsigned short* wvb = (unsigned short*)(ws + (2u << 20));          // 12.28MB@ 2M

    setup_kernel<<<NBATCH + CONV_BLOCKS, 256, 0, stream>>>(zi, latent, Wt, bt, Wv, bv,
                                                           zsb, wvb, bvs, S);

    gemm_lse_kernel<<<dim3(GRIDX, GRIDY), 256, 0, stream>>>(zsb, wvb, bvs, S);

    tail_kernel<<<MROWS / 4, 256, 0, stream>>>(zsb, Wv, bv, y, S, out);
}

// Round 14
// 196.731 us; speedup vs baseline: 1.1798x; 1.0490x over previous
//
#include <hip/hip_runtime.h>
#include <hip/hip_bf16.h>
#include <hip/hip_fp8.h>

#define EMBED 128
#define TSTEPS 128
#define NBATCH 32
#define VDIM 50257
#define VPAD 50304            // 786 groups * 64 cols
#define MROWS 4096            // NBATCH * TSTEPS
#define NGROUPS 786           // VPAD / 64
#define GRIDX 64              // B-sweep split: 786 = 64*12 + 18
#define GRIDY 16              // 256-row M slices
#define MAXGRP 13             // max groups per x-block
#define CONV_N4 ((VDIM * EMBED) / 4)          // 1608224 float4 elements
#define CONV_BLOCKS ((CONV_N4 + 255) / 256)   // 6283

static constexpr float LOG2E = 1.4426950408889634f;
static constexpr float LN2   = 0.6931471805599453f;

__device__ __forceinline__ float fast_exp2(float x) {
#if __has_builtin(__builtin_amdgcn_exp2f)
    return __builtin_amdgcn_exp2f(x);
#else
    return exp2f(x);
#endif
}
__device__ __forceinline__ float fast_log2(float x) {
#if __has_builtin(__builtin_amdgcn_logf)
    return __builtin_amdgcn_logf(x);
#else
    return log2f(x);
#endif
}
__device__ __forceinline__ float fast_rcp(float x) {
#if __has_builtin(__builtin_amdgcn_rcpf)
    return __builtin_amdgcn_rcpf(x);
#else
    return 1.0f / x;
#endif
}
// Branch-free tanh with Newton-refined reciprocal (R12-verified: absmax
// 0.1875 vs libm's 0.125, saved ~8us total by avoiding libm's divergent
// poly/exp paths in the scan).
__device__ __forceinline__ float fast_tanh_nr(float x) {
    x = fminf(20.0f, fmaxf(-20.0f, x));
    float t = fast_exp2((2.0f * LOG2E) * x);    // e^{2x}
    float u = t + 1.0f;
    float r = fast_rcp(u);
    r = r * fmaf(-u, r, 2.0f);                  // Newton: error ~ulp^2
    return (t - 1.0f) * r;
}
__device__ __forceinline__ unsigned short f2bf_raw(float f) {
    __hip_bfloat16 h = __float2bfloat16(f);
    union { __hip_bfloat16 b; unsigned short u; } cvt;
    cvt.b = h;
    return cvt.u;
}
__device__ __forceinline__ float bf_raw2f(unsigned short u) {
    union { unsigned int u; float f; } cvt;
    cvt.u = ((unsigned int)u) << 16;
    return cvt.f;
}
// pack 2 floats -> 2 fp8 e4m3 bytes into the selected half of `old`.
// R13 compile fix: the word-select operand of cvt_pk_fp8 must be an ICE,
// so HI is a template parameter (constant inside the body).
template <bool HI>
__device__ __forceinline__ int pk_fp8(float a, float b, int old) {
#if __has_builtin(__builtin_amdgcn_cvt_pk_fp8_f32)
    return __builtin_amdgcn_cvt_pk_fp8_f32(a, b, old, HI);
#else
    __hip_fp8_e4m3 x(a), y(b);
    int v = (int)(unsigned char)x.__x | ((int)(unsigned char)y.__x << 8);
    return HI ? ((old & 0xffff) | (v << 16)) : ((old & ~0xffff) | v);
#endif
}

// ---------------------------------------------------------------------------
// K0 (fused setup): blocks [0,32) = sequential scan (one batch chain each);
// blocks [32, 32+CONV_BLOCKS) convert Wv fp32 -> fp8 e4m3 (+ zero pad rows),
// build bvs[j] = bv[j]*log2e (pad -> -1e30), and zero S.
//
// Scan = R12-verified structure (e = tid>>1, h = tid&1, one shfl_xor,
// ping-pong z, ONE barrier/step, fast_tanh_nr, 32 KB LDS stash).  The fp32
// summation order ((zc+sA)+sB)+bt is IDENTICAL to rounds 1-12 — the
// recurrence trajectory must not be perturbed (round-4 lesson).  Bulk store
// emits BOTH bf16 (tail's fp32 target dot) and fp8 (gemm A operand).
// NOTE (round-9): no cross-block producer/consumer sync — device-scope
// fences force L2 writeback/invalidate (5.6x regression).
// ---------------------------------------------------------------------------
__global__ __launch_bounds__(256) void setup_kernel(const int* __restrict__ zi,
                                                    const float* __restrict__ latent,
                                                    const float* __restrict__ Wt,
                                                    const float* __restrict__ bt,
                                                    const float* __restrict__ Wv,
                                                    const float* __restrict__ bv,
                                                    unsigned short* __restrict__ zsb,
                                                    unsigned char* __restrict__ zsa8,
                                                    unsigned char* __restrict__ wv8,
                                                    float* __restrict__ bvs,
                                                    float* __restrict__ S) {
    if (blockIdx.x >= NBATCH) {
        const int cb = blockIdx.x - NBATCH;
        if (cb == 0) {                      // zero the S accumulator
#pragma unroll
            for (int i = 0; i < MROWS / 256; i++)
                S[i * 256 + threadIdx.x] = 0.f;
        }
        if (cb == 1) {                      // zero fp8 pad rows of wv8
            const int base  = VDIM * EMBED / 4;          // first pad uint
            const int npad  = (VPAD - VDIM) * EMBED / 4; // 1504 uints
            for (int i = threadIdx.x; i < npad; i += 256)
                reinterpret_cast<unsigned int*>(wv8)[base + i] = 0u;
        }
        const int idx = cb * 256 + threadIdx.x;
        if (idx < VPAD)                     // prescaled, padded bias
            bvs[idx] = (idx < VDIM) ? bv[idx] * LOG2E : -1e30f;
        if (idx < CONV_N4) {
            float4 v = reinterpret_cast<const float4*>(Wv)[idx];
            int p = pk_fp8<false>(v.x, v.y, 0);
            p = pk_fp8<true>(v.z, v.w, p);
            reinterpret_cast<unsigned int*>(wv8)[idx] = (unsigned int)p;
        }
        return;
    }

    // ---- scan path: one block per batch element ----
    __shared__ float zbuf[2][EMBED];
    __shared__ unsigned short zstash[TSTEPS * EMBED];   // 32 KB bf16 stash
    const int b = blockIdx.x;
    const int e = threadIdx.x >> 1;     // output element 0..127
    const int h = threadIdx.x & 1;      // k-half

    // cache Wt[e][h*64 .. h*64+63] in registers (64 VGPRs)
    float4 wrow[16];
    const float4* wt4 = reinterpret_cast<const float4*>(Wt + e * EMBED + h * 64);
#pragma unroll
    for (int i = 0; i < 16; i++) wrow[i] = wt4[i];
    const float bte = bt[e];

    if (h == 0) zbuf[0][e] = latent[zi[b] * EMBED + e];
    __syncthreads();

    int cur = 0;
    for (int t = 0; t < TSTEPS; t++) {
        const float zc = zbuf[cur][e];      // lane pairs broadcast
        if (h == 0)                         // stash pre-update z (bf16 * log2e)
            zstash[t * EMBED + e] = f2bf_raw(zc * LOG2E);

        // half-dot over k in [h*64, h*64+64)
        const float4* z4 = reinterpret_cast<const float4*>(&zbuf[cur][h * 64]);
        float4 acc = {0.f, 0.f, 0.f, 0.f};
#pragma unroll
        for (int i = 0; i < 16; i++) {
            float4 zv = z4[i];
            acc.x += zv.x * wrow[i].x;
            acc.y += zv.y * wrow[i].y;
            acc.z += zv.z * wrow[i].z;
            acc.w += zv.w * wrow[i].w;
        }
        float v = acc.x + acc.y + acc.z + acc.w;
        float p = __shfl_xor(v, 1);         // partner half (same e, other h)
        float sA = h ? p : v;
        float sB = h ? v : p;
        // summation order identical to rounds 1-12 (same dot trajectory)
        float znew = fast_tanh_nr(((zc + sA) + sB) + bte);
        if (h == 0) zbuf[cur ^ 1][e] = znew;
        __syncthreads();                    // lgkmcnt-only drain (no stores)
        cur ^= 1;
    }

    // bulk store: bf16 copy (tail) + fp8 conversion (gemm A), coalesced
    uint4* dstb = reinterpret_cast<uint4*>(zsb + (long)b * TSTEPS * EMBED);
    uint2* dsta = reinterpret_cast<uint2*>(zsa8 + (long)b * TSTEPS * EMBED);
    const uint4* src = reinterpret_cast<const uint4*>(zstash);
    for (int i = threadIdx.x; i < TSTEPS * EMBED / 8; i += 256) {
        uint4 w = src[i];                   // 8 bf16 (z * log2e)
        dstb[i] = w;
        float f0 = bf_raw2f(w.x & 0xffff), f1 = bf_raw2f(w.x >> 16);
        float f2 = bf_raw2f(w.y & 0xffff), f3 = bf_raw2f(w.y >> 16);
        float f4 = bf_raw2f(w.z & 0xffff), f5 = bf_raw2f(w.z >> 16);
        float f6 = bf_raw2f(w.w & 0xffff), f7 = bf_raw2f(w.w >> 16);
        int lo = pk_fp8<false>(f0, f1, 0); lo = pk_fp8<true>(f2, f3, lo);
        int hi = pk_fp8<false>(f4, f5, 0); hi = pk_fp8<true>(f6, f7, hi);
        uint2 o; o.x = (unsigned int)lo; o.y = (unsigned int)hi;
        dsta[i] = o;
    }
}

// ---------------------------------------------------------------------------
// K1: fused GEMM + sum-of-exp2, fp8 operands (round-14 = round-13 retry).
// R6-R12 showed the bf16 version pinned at ~74us: per residency round the
// 16KB/group B staging drain (~1170 cyc/CU) EQUALS the MFMA time — the
// barrier serializes them.  fp8 halves the staged bytes (8KB tiles), halves
// FETCH, and halves A-frag VGPRs, at the SAME MFMA shape/rate
// (mfma_f32_16x16x32_fp8_fp8 = bf16 rate; per-logit noise ~0.02 << budget).
// Structure otherwise R7-verbatim: 4 waves x 64 rows = 256 rows x 12-13
// groups of 64 N-cols, double-buffered LDS, one barrier per group, LDS bias
// slice, zero-C init, sums = fma(exp2(d), exp2(bias), sums).
// fp8 LDS layout (16B granule, XOR-8 swizzle): phys granule G' = G ^ (r&7);
// fragment ds_read_b64 at r*128 + ((q>>1)^(r&7))*16 + (q&1)*8 -> 16 lanes
// per quad hit distinct bank pairs (free 2-way only).
// A/B fragment (fp8 16x16x32): lane holds [m|n = lane&15][k = quad*8+j],
// j=0..7 packed LSB-first in one i64.  D: row=(lane>>4)*4+r, col=lane&15.
// ---------------------------------------------------------------------------
typedef __attribute__((ext_vector_type(4))) float f32x4;

__global__ __launch_bounds__(256) void gemm_lse_kernel(const unsigned char* __restrict__ zsa8,
                                                       const unsigned char* __restrict__ wv8,
                                                       const float* __restrict__ bvs,
                                                       float* __restrict__ S) {
    __shared__ unsigned char ldsb[2][8192];  // 2 x 8 KB fp8 B tiles
    __shared__ float ldsbias[MAXGRP * 64];   // this block's bias slice (3.3 KB)

    const int lane  = threadIdx.x & 63;
    const int wave  = threadIdx.x >> 6;
    const int col16 = lane & 15;
    const int quad  = lane >> 4;
    const int mbase = blockIdx.y * 256 + wave * 64;

    // group range for this x-block: 786 = 64*12 + 18
    const int x  = blockIdx.x;
    const int g0 = x * 12 + min(x, 18);
    const int g1 = g0 + 12 + (x < 18 ? 1 : 0);
    const int nbias = (g1 - g0) * 64;

    // prologue: stage this block's bias slice into LDS
    for (int i = threadIdx.x; i < nbias; i += 256)
        ldsbias[i] = bvs[g0 * 64 + i];

    // A fragments: 4 M-subtiles x 4 K-chunks, one i64 each (32 VGPRs)
    unsigned long long a[4][4];
#pragma unroll
    for (int s = 0; s < 4; s++)
#pragma unroll
        for (int c = 0; c < 4; c++)
            a[s][c] = *reinterpret_cast<const unsigned long long*>(
                zsa8 + (long)(mbase + s * 16 + col16) * EMBED + c * 32 + quad * 8);

    float sums[16];
#pragma unroll
    for (int i = 0; i < 16; i++) sums[i] = 0.f;

    // stage group g's 8 KB fp8 B-tile into ldsb[buf] (XOR-8 swizzle)
    auto stage = [&](int buf, int g) {
#pragma unroll
        for (int j = 0; j < 2; j++) {
            const int rr = (wave * 2 + j) * 8 + (lane >> 3);   // B-row 0..63
            const int G  = (lane & 7) ^ (rr & 7);              // logical granule
            const unsigned char* gp = wv8 + (long)(g * 64 + rr) * EMBED + G * 16;
            __builtin_amdgcn_global_load_lds(
                (const __attribute__((address_space(1))) void*)gp,
                (__attribute__((address_space(3))) void*)&ldsb[buf][(wave * 2 + j) * 1024],
                16, 0, 0);
        }
    };

    int cur = 0;
    stage(0, g0);

    const f32x4 dzero = {0.f, 0.f, 0.f, 0.f};

    for (int g = g0; g < g1; g++) {
        __syncthreads();                     // buf[cur] + bias staged; prev reads done
        if (g + 1 < g1) stage(cur ^ 1, g + 1);

        const float* biasg = &ldsbias[(g - g0) * 64];

#pragma unroll
        for (int c = 0; c < 4; c++) {
            // fragment reads: row r = c*16+col16; byte offset q_abs*8
            // (q_abs = kc*4+quad); phys = ((q_abs>>1)^(r&7))*16 + (q_abs&1)*8
            const unsigned char* rowp = &ldsb[cur][(c * 16 + col16) * 128];
            const int r7 = col16 & 7;
            unsigned long long bf[4];
#pragma unroll
            for (int kc = 0; kc < 4; kc++) {
                const int q_abs = kc * 4 + quad;
                bf[kc] = *reinterpret_cast<const unsigned long long*>(
                    rowp + (((q_abs >> 1) ^ r7) * 16) + ((q_abs & 1) * 8));
            }

            const float eb = fast_exp2(biasg[c * 16 + col16]);  // 0 for pad

            // kc-outer, s-inner: consecutive MFMAs are independent (4 chains)
            f32x4 d[4];
#pragma unroll
            for (int s = 0; s < 4; s++)
                d[s] = __builtin_amdgcn_mfma_f32_16x16x32_fp8_fp8(
                    (long long)a[s][0], (long long)bf[0], dzero, 0, 0, 0);
#pragma unroll
            for (int kc = 1; kc < 4; kc++)
#pragma unroll
                for (int s = 0; s < 4; s++)
                    d[s] = __builtin_amdgcn_mfma_f32_16x16x32_fp8_fp8(
                        (long long)a[s][kc], (long long)bf[kc], d[s], 0, 0, 0);

#pragma unroll
            for (int s = 0; s < 4; s++)
#pragma unroll
                for (int r = 0; r < 4; r++)
                    sums[s * 4 + r] = fmaf(fast_exp2(d[s][r]), eb, sums[s * 4 + r]);
        }
        cur ^= 1;
    }

    // reduce partial sums over the 16 columns, one atomic per row per block
#pragma unroll
    for (int s = 0; s < 4; s++) {
#pragma unroll
        for (int r = 0; r < 4; r++) {
            float v = sums[s * 4 + r];
            v += __shfl_xor(v, 1);
            v += __shfl_xor(v, 2);
            v += __shfl_xor(v, 4);
            v += __shfl_xor(v, 8);
            if (col16 == 0)
                atomicAdd(&S[mbase + s * 16 + quad * 4 + r], v);
        }
    }
}

// ---------------------------------------------------------------------------
// K2: yp[row] = ln2*(dot_scaled - log2(S[row])) + bv[y[row]], where
// dot_scaled = (bf16 zsb row) . (fp32 Wv[y] row)  -- zsb is z*log2e in bf16;
// bf16 quantization adds only ~1e-3 to the target dot.
// One wave per row; lane l handles elements {2l, 2l+1}.
// ---------------------------------------------------------------------------
__global__ __launch_bounds__(256) void tail_kernel(const unsigned short* __restrict__ zsb,
                                                   const float* __restrict__ Wv,
                                                   const float* __restrict__ bv,
                                                   const int* __restrict__ y,
                                                   const float* __restrict__ S,
                                                   float* __restrict__ out) {
    const int row  = blockIdx.x * 4 + (threadIdx.x >> 6);
    const int lane = threadIdx.x & 63;
    const int yv = y[row];
    const ushort2* zr = reinterpret_cast<const ushort2*>(zsb + (long)row * EMBED);
    const float2*  wr = reinterpret_cast<const float2*>(Wv + (long)yv * EMBED);
    ushort2 z2 = zr[lane];
    float2  w2 = wr[lane];
    float v = bf_raw2f(z2.x) * w2.x + bf_raw2f(z2.y) * w2.y;
    v += __shfl_xor(v, 32);
    v += __shfl_xor(v, 16);
    v += __shfl_xor(v, 8);
    v += __shfl_xor(v, 4);
    v += __shfl_xor(v, 2);
    v += __shfl_xor(v, 1);
    if (lane == 0)
        out[row] = LN2 * (v - fast_log2(S[row])) + bv[yv];
}

// ---------------------------------------------------------------------------
extern "C" void kernel_launch(void* const* d_in, const int* in_sizes, int n_in,
                              void* d_out, int out_size, void* d_ws, size_t ws_size,
                              hipStream_t stream) {
    const int*   zi     = (const int*)d_in[0];
    const int*   y      = (const int*)d_in[1];
    const float* latent = (const float*)d_in[2];
    const float* Wt     = (const float*)d_in[3];
    const float* bt     = (const float*)d_in[4];
    const float* Wv     = (const float*)d_in[5];
    const float* bv     = (const float*)d_in[6];
    float* out = (float*)d_out;

    char* ws = (char*)d_ws;
    // workspace layout (~8.3 MB total):
    unsigned short* zsb  = (unsigned short*)ws;                        // 1 MB   @ 0
    unsigned char*  zsa8 = (unsigned char*)(ws + (1u << 20));          // 0.5 MB @ 1M
    float*          S    = (float*)(ws + 1536u * 1024);                // 16 KB  @ 1.5M
    float*          bvs  = (float*)(ws + 1536u * 1024 + (64u << 10));  // 197 KB @ 1.5M+64K
    unsigned char*  wv8  = (unsigned char*)(ws + (2u << 20));          // 6.14MB @ 2M

    setup_kernel<<<NBATCH + CONV_BLOCKS, 256, 0, stream>>>(zi, latent, Wt, bt, Wv, bv,
                                                           zsb, zsa8, wv8, bvs, S);

    gemm_lse_kernel<<<dim3(GRIDX, GRIDY), 256, 0, stream>>>(zsa8, wv8, bvs, S);

    tail_kernel<<<MROWS / 4, 256, 0, stream>>>(zsb, Wv, bv, y, S, out);
}